// Round 5
// baseline (166.216 us; speedup 1.0000x reference)
//
#include <hip/hip_runtime.h>

typedef _Float16 f16;
typedef __attribute__((ext_vector_type(8))) _Float16 f16x8;
typedef __attribute__((ext_vector_type(4))) float f32x4;
typedef unsigned int u32;

#define S_      4
#define NPER    12500
#define NF      1024
#define HID     256
#define NSTRUCT 500
#define TM      64

#define WAIT_LGKM() asm volatile("s_waitcnt lgkmcnt(0)" ::: "memory")
#define SCHED0()    __builtin_amdgcn_sched_barrier(0)
#define BARRIER()   do { __builtin_amdgcn_s_barrier(); SCHED0(); } while (0)

// ---------------------------------------------------------------------------
// Fused weight transpose + fp32->fp16 (all 3 layers, 1 launch) -- unchanged.
// ---------------------------------------------------------------------------
__global__ __launch_bounds__(256) void transpose_all_kernel(
    const float* __restrict__ W1, const float* __restrict__ W2,
    const float* __restrict__ W3,
    f16* __restrict__ w1t, f16* __restrict__ w2t, f16* __restrict__ w3t)
{
  const int z = blockIdx.z;            // layer*4 + species
  const int layer = z >> 2, sp = z & 3;
  const float* in; f16* out; int K;
  if (layer == 0)      { in = W1; out = w1t; K = NF;  }
  else if (layer == 1) { in = W2; out = w2t; K = HID; }
  else                 { in = W3; out = w3t; K = HID; }
  if (blockIdx.x * 64 >= K) return;

  __shared__ float tile[64][65];
  const float* inp = in + (size_t)sp * K * HID;
  f16* outp = out + (size_t)sp * K * HID;
  const int k0 = blockIdx.x * 64;
  const int n0 = blockIdx.y * 64;
  const int t = threadIdx.x;
  {
    const int lk = t >> 2;
    const int nq = (t & 3) * 16;
    const float* src = inp + (size_t)(k0 + lk) * HID + n0 + nq;
    #pragma unroll
    for (int i = 0; i < 4; ++i) {
      float4 v = *(const float4*)(src + i * 4);
      tile[lk][nq + i * 4 + 0] = v.x;
      tile[lk][nq + i * 4 + 1] = v.y;
      tile[lk][nq + i * 4 + 2] = v.z;
      tile[lk][nq + i * 4 + 3] = v.w;
    }
  }
  __syncthreads();
  {
    const int ln = t >> 2;
    const int kq = (t & 3) * 16;
    f16* dst = outp + (size_t)(n0 + ln) * K + k0 + kq;
    f16x8 a, b;
    #pragma unroll
    for (int j = 0; j < 8; ++j) a[j] = (f16)tile[kq + j][ln];
    #pragma unroll
    for (int j = 0; j < 8; ++j) b[j] = (f16)tile[kq + 8 + j][ln];
    *(f16x8*)dst = a;
    *(f16x8*)(dst + 8) = b;
  }
}

// ---------------------------------------------------------------------------
// Fused MLP R12 = R11 structure + latency-matched prefetch covers:
//  - pa (features, HBM ~900cy): 4 rotating register sets; pa(c+5) issued at
//    phase c, used at phase c+4 => ~3.3-phase cover (R11: ~1.5 => stalled).
//  - Hidden B (L2 ~250cy): 3-slot rotation, prefetch distance 3 chunks
//    (issue g+3 after chunk g's MFMA => ~2-chunk cover; R11: ~0.7 chunk).
//    W2(0..2) pre-issued during L1 phases 14/15.
//  - Everything else unchanged: 512thr/8 waves, wave tile 64x32, B L2->regs,
//    fp16 ds_write A staging (XOR 8-slot layout), compiler-counted vm waits,
//    32 KB arena, barrier-free hidden layers.
// ---------------------------------------------------------------------------

__device__ __forceinline__ void zero_acc(f32x4 (&acc)[4][2]) {
  #pragma unroll
  for (int a = 0; a < 4; ++a)
    #pragma unroll
    for (int b = 0; b < 2; ++b)
      #pragma unroll
      for (int j = 0; j < 4; ++j) acc[a][b][j] = 0.f;
}

// B fragments L2 -> regs: 4 x 16B per lane per KC=64 chunk.
__device__ __forceinline__ void load_b64(f16x8 (&bf)[4], const f16* wsrc, int c,
                                         int K, int w, int g, int l15)
{
  #pragma unroll
  for (int ks = 0; ks < 2; ++ks)
    #pragma unroll
    for (int bt = 0; bt < 2; ++bt) {
      const int nn = w * 32 + bt * 16 + l15;
      bf[ks * 2 + bt] = *(const f16x8*)(wsrc + (size_t)nn * K + c * 64 + (ks * 4 + g) * 8);
    }
}

// Features prefetch: thread handles row t>>3, k-slot t&7 (8 floats).
__device__ __forceinline__ void load_pa(float4 (&pa)[2], const float* fsrcT, int c)
{
  pa[0] = *(const float4*)(fsrcT + c * 64);
  pa[1] = *(const float4*)(fsrcT + c * 64 + 4);
}

// Features chunk [64 r][64 k] fp32->fp16 into aS. Row = 128B = 8 slots of
// 16B; phys slot p at row r holds logical k-slot p^(r&7). One ds_write/thr.
__device__ __forceinline__ void stage_feat64(char* aS, const float4 (&pa)[2], int t)
{
  const int r = t >> 3;
  f16x8 hv;
  hv[0]=(f16)pa[0].x; hv[1]=(f16)pa[0].y; hv[2]=(f16)pa[0].z; hv[3]=(f16)pa[0].w;
  hv[4]=(f16)pa[1].x; hv[5]=(f16)pa[1].y; hv[6]=(f16)pa[1].z; hv[7]=(f16)pa[1].w;
  const int slog = t & 7;
  const int p = slog ^ (r & 7);
  *(f16x8*)(aS + r * 128 + p * 16) = hv;
}

// L1 compute: one KC=64 chunk, A from LDS (proven layout), B regs. 16 MFMA.
__device__ __forceinline__ void mfma64_ab(f32x4 (&acc)[4][2], const char* aS,
                                          const f16x8 (&bf)[4], int g, int l15)
{
  #pragma unroll
  for (int ks = 0; ks < 2; ++ks) {
    f16x8 af[4];
    #pragma unroll
    for (int at = 0; at < 4; ++at) {
      const int rr = at * 16 + l15;
      const int p  = (ks * 4 + g) ^ (rr & 7);
      af[at] = *(const f16x8*)(aS + rr * 128 + p * 16);
    }
    #pragma unroll
    for (int at = 0; at < 4; ++at)
      #pragma unroll
      for (int bt = 0; bt < 2; ++bt)
        acc[at][bt] = __builtin_amdgcn_mfma_f32_16x16x32_f16(af[at], bf[ks*2+bt], acc[at][bt], 0, 0, 0);
  }
}

// Hidden compute: KC=64 chunk, A = hL fp16 (xor (row&7)<<4 layout), B regs.
__device__ __forceinline__ void mfma64_h(f32x4 (&acc)[4][2], const char* hL, int cH,
                                         const f16x8 (&bf)[4], int g, int l15)
{
  #pragma unroll
  for (int ks = 0; ks < 2; ++ks) {
    f16x8 af[4];
    #pragma unroll
    for (int at = 0; at < 4; ++at) {
      const int rr = at * 16 + l15;
      af[at] = *(const f16x8*)(hL + ((rr * 512 + cH * 128 + ks * 64 + g * 16) ^ ((rr & 7) << 4)));
    }
    #pragma unroll
    for (int at = 0; at < 4; ++at)
      #pragma unroll
      for (int bt = 0; bt < 2; ++bt)
        acc[at][bt] = __builtin_amdgcn_mfma_f32_16x16x32_f16(af[at], bf[ks*2+bt], acc[at][bt], 0, 0, 0);
  }
}

__device__ __forceinline__ void silu_store(f32x4 (&acc)[4][2],
                                           const float* __restrict__ bias,
                                           char* hL, int w, int lane)
{
  const int g = lane >> 4, l15 = lane & 15;
  #pragma unroll
  for (int bt = 0; bt < 2; ++bt) {
    const int col = w * 32 + bt * 16 + l15;
    const float b = bias[col];
    #pragma unroll
    for (int at = 0; at < 4; ++at) {
      #pragma unroll
      for (int j = 0; j < 4; ++j) {
        const int row = at * 16 + g * 4 + j;   // m89-verified C/D mapping
        float x = acc[at][bt][j] + b;
        x = x * __builtin_amdgcn_rcpf(1.f + __expf(-x));
        *(f16*)(hL + (((row * HID + col) * 2) ^ ((row & 7) << 4))) = (f16)x;
      }
    }
  }
}

// Steady L1 phase: issue B(c+1) (pre-stall), stage A(c+1) from pa(c+1)
// (4-deep cover), refill PAS <- pa(c+5), compute chunk c, drain, barrier.
#define L1_PH(c, AScur, ASstg, BFcur, BFnxt, PAS, DOPA, DOB)    \
  do {                                                           \
    if (DOB)  load_b64(BFnxt, w1s, (c) + 1, NF, w, g, l15);      \
    stage_feat64(ASstg, PAS, t);                                 \
    if (DOPA) load_pa(PAS, fsrcT, (c) + 5);                      \
    mfma64_ab(acc, AScur, BFcur, g, l15);                        \
    WAIT_LGKM(); BARRIER();                                      \
  } while (0)

__global__ __launch_bounds__(512, 4) void mlp_fused_kernel(
    const float* __restrict__ feats,
    const float* __restrict__ b1g,
    const float* __restrict__ b2g,
    const float* __restrict__ b3g,
    const float* __restrict__ w4g,
    const float* __restrict__ b4g,
    const int*   __restrict__ sidxg,
    const f16*   __restrict__ w1t,
    const f16*   __restrict__ w2t,
    const f16*   __restrict__ w3t,
    float*       __restrict__ outg)
{
  __shared__ char arena[32 * 1024];
  char* aS0 = arena;                 // L1 A dbuf: 2 x 8 KB fp16
  char* aS1 = arena + 8 * 1024;
  char* hL  = arena;                 // hidden: h [64][256] fp16, 32 KB overlay

  const int s    = blockIdx.y;
  const int row0 = blockIdx.x * TM;
  const int t    = threadIdx.x;
  const int lane = t & 63;
  const int w    = t >> 6;           // 0..7; wave w owns output cols w*32..+31
  const int g    = lane >> 4;
  const int l15  = lane & 15;

  const int gr   = row0 + (t >> 3);  // staging/L4 row of this thread
  const bool valid = gr < NPER;
  const int grc  = valid ? gr : (NPER - 1);
  const float* fsrcT = feats + ((size_t)s * NPER + grc) * NF + (t & 7) * 8;
  const f16*   w1s   = w1t + (size_t)s * HID * NF;
  const f16*   w2s   = w2t + (size_t)s * HID * HID;
  const f16*   w3s   = w3t + (size_t)s * HID * HID;

  f32x4 acc[4][2];
  f16x8 bfA[4], bfB[4], bfC[4];      // bfC live only from L1 phase 15 on
  zero_acc(acc);

  // ===== L1 prologue: B(0) in flight; pa(1..4) in 4 sets; A(0) staged =====
  float4 pa0[2], paS0[2], paS1[2], paS2[2], paS3[2];
  load_b64(bfA, w1s, 0, NF, w, g, l15);
  load_pa(pa0,  fsrcT, 0);
  load_pa(paS0, fsrcT, 1);
  load_pa(paS1, fsrcT, 2);
  load_pa(paS2, fsrcT, 3);
  load_pa(paS3, fsrcT, 4);
  stage_feat64(aS0, pa0, t);         // compiler waits pa0's 2 loads only
  WAIT_LGKM(); BARRIER();

  // ===== L1: 16 phases, KC=64, dbuf A, reg-dbuf B, 4-deep pa rotation =====
  L1_PH(0,  aS0, aS1, bfA, bfB, paS0, 1, 1);  // use pa(1); paS0 <- pa(5)
  L1_PH(1,  aS1, aS0, bfB, bfA, paS1, 1, 1);
  L1_PH(2,  aS0, aS1, bfA, bfB, paS2, 1, 1);
  L1_PH(3,  aS1, aS0, bfB, bfA, paS3, 1, 1);
  L1_PH(4,  aS0, aS1, bfA, bfB, paS0, 1, 1);
  L1_PH(5,  aS1, aS0, bfB, bfA, paS1, 1, 1);
  L1_PH(6,  aS0, aS1, bfA, bfB, paS2, 1, 1);
  L1_PH(7,  aS1, aS0, bfB, bfA, paS3, 1, 1);
  L1_PH(8,  aS0, aS1, bfA, bfB, paS0, 1, 1);
  L1_PH(9,  aS1, aS0, bfB, bfA, paS1, 1, 1);
  L1_PH(10, aS0, aS1, bfA, bfB, paS2, 1, 1);  // paS2 <- pa(15), last refill
  L1_PH(11, aS1, aS0, bfB, bfA, paS3, 0, 1);  // use pa(12)
  L1_PH(12, aS0, aS1, bfA, bfB, paS0, 0, 1);  // use pa(13)
  L1_PH(13, aS1, aS0, bfB, bfA, paS1, 0, 1);  // use pa(14)
  L1_PH(14, aS0, aS1, bfA, bfB, paS2, 0, 1);  // use pa(15); B(15) -> bfB
  { // phase 15: W2(0) early; compute aS1/bfB=B(15); W2(1),W2(2) post-MFMA
    load_b64(bfA, w2s, 0, HID, w, g, l15);    // hidden slot S0
    mfma64_ab(acc, aS1, bfB, g, l15);
    load_b64(bfB, w2s, 1, HID, w, g, l15);    // hidden slot S1
    load_b64(bfC, w2s, 2, HID, w, g, l15);    // hidden slot S2
    WAIT_LGKM(); BARRIER();
  }

  // ===== L1 -> L2: write h over dead A buffers =====
  silu_store(acc, b1g + s * HID, hL, w, lane);
  zero_acc(acc);
  WAIT_LGKM(); BARRIER();

  // ===== Layer 2: 4 chunks KC=64, barrier-free; 3-slot B, prefetch g+3 =====
  mfma64_h(acc, hL, 0, bfA, g, l15);  load_b64(bfA, w2s, 3, HID, w, g, l15);
  mfma64_h(acc, hL, 1, bfB, g, l15);  load_b64(bfB, w3s, 0, HID, w, g, l15);
  mfma64_h(acc, hL, 2, bfC, g, l15);  load_b64(bfC, w3s, 1, HID, w, g, l15);
  mfma64_h(acc, hL, 3, bfA, g, l15);  load_b64(bfA, w3s, 2, HID, w, g, l15);
  BARRIER();                         // all waves done reading hL
  silu_store(acc, b2g + s * HID, hL, w, lane);
  zero_acc(acc);
  WAIT_LGKM(); BARRIER();            // hL published

  // ===== Layer 3: 4 chunks, barrier-free; rotation continues =====
  mfma64_h(acc, hL, 0, bfB, g, l15);  load_b64(bfB, w3s, 3, HID, w, g, l15);
  mfma64_h(acc, hL, 1, bfC, g, l15);
  mfma64_h(acc, hL, 2, bfA, g, l15);
  mfma64_h(acc, hL, 3, bfB, g, l15);
  BARRIER();
  silu_store(acc, b3g + s * HID, hL, w, lane);
  WAIT_LGKM(); BARRIER();

  // ===== Layer 4: e = h @ W4 + b4; segment-sum via atomicAdd =====
  {
    const int row = t >> 3;
    const int q   = t & 7;
    const float* w4 = w4g + s * HID;
    float sum = 0.f;
    #pragma unroll
    for (int j8 = 0; j8 < 32; j8 += 8) {
      const int k = q * 32 + j8;
      f16x8 hv = *(const f16x8*)(hL + (((row * HID + k) * 2) ^ ((row & 7) << 4)));
      float4 wa = *(const float4*)(w4 + k);
      float4 wb = *(const float4*)(w4 + k + 4);
      sum += (float)hv[0] * wa.x + (float)hv[1] * wa.y + (float)hv[2] * wa.z + (float)hv[3] * wa.w
           + (float)hv[4] * wb.x + (float)hv[5] * wb.y + (float)hv[6] * wb.z + (float)hv[7] * wb.w;
    }
    sum += __shfl_xor(sum, 1);
    sum += __shfl_xor(sum, 2);
    sum += __shfl_xor(sum, 4);
    if (q == 0 && valid) {
      atomicAdd(&outg[sidxg[s * NPER + gr]], sum + b4g[s]);
    }
  }
}

// ---------------------------------------------------------------------------
extern "C" void kernel_launch(void* const* d_in, const int* in_sizes, int n_in,
                              void* d_out, int out_size, void* d_ws, size_t ws_size,
                              hipStream_t stream)
{
  const float* feats = (const float*)d_in[0];
  const float* W1    = (const float*)d_in[1];
  const float* b1    = (const float*)d_in[2];
  const float* W2    = (const float*)d_in[3];
  const float* b2    = (const float*)d_in[4];
  const float* W3    = (const float*)d_in[5];
  const float* b3    = (const float*)d_in[6];
  const float* W4    = (const float*)d_in[7];
  const float* b4    = (const float*)d_in[8];
  const int*   sidx  = (const int*)d_in[9];
  float* out = (float*)d_out;

  f16* w1t = (f16*)d_ws;                              // [S][256][1024] fp16
  f16* w2t = w1t + (size_t)S_ * HID * NF;             // [S][256][256]  fp16
  f16* w3t = w2t + (size_t)S_ * HID * HID;            // [S][256][256]  fp16

  hipMemsetAsync(d_out, 0, NSTRUCT * sizeof(float), stream);
  transpose_all_kernel<<<dim3(16, 4, 12), 256, 0, stream>>>(W1, W2, W3, w1t, w2t, w3t);
  mlp_fused_kernel<<<dim3((NPER + TM - 1) / TM, S_), 512, 0, stream>>>(
      feats, b1, b2, b3, W4, b4, sidx, w1t, w2t, w3t, out);
}

// Round 6
// 108.292 us; speedup vs baseline: 1.5349x; 1.5349x over previous
//
#include <hip/hip_runtime.h>

typedef _Float16 f16;
typedef __attribute__((ext_vector_type(8))) _Float16 f16x8;
typedef __attribute__((ext_vector_type(4))) float f32x4;
typedef unsigned int u32;

#define S_      4
#define NPER    12500
#define NF      1024
#define HID     256
#define NSTRUCT 500
#define TM      64

#define GLB __attribute__((address_space(1)))
#define AS3 __attribute__((address_space(3)))

#define WAIT_VM(N)  asm volatile("s_waitcnt vmcnt(" #N ")" ::: "memory")
#define WAIT_LGKM() asm volatile("s_waitcnt lgkmcnt(0)" ::: "memory")
#define SCHED0()    __builtin_amdgcn_sched_barrier(0)
#define BARRIER()   do { __builtin_amdgcn_s_barrier(); SCHED0(); } while (0)

// ---------------------------------------------------------------------------
// Fused weight transpose + fp32->fp16 (all 3 layers, 1 launch)
// ---------------------------------------------------------------------------
__global__ __launch_bounds__(256) void transpose_all_kernel(
    const float* __restrict__ W1, const float* __restrict__ W2,
    const float* __restrict__ W3,
    f16* __restrict__ w1t, f16* __restrict__ w2t, f16* __restrict__ w3t)
{
  const int z = blockIdx.z;            // layer*4 + species
  const int layer = z >> 2, sp = z & 3;
  const float* in; f16* out; int K;
  if (layer == 0)      { in = W1; out = w1t; K = NF;  }
  else if (layer == 1) { in = W2; out = w2t; K = HID; }
  else                 { in = W3; out = w3t; K = HID; }
  if (blockIdx.x * 64 >= K) return;

  __shared__ float tile[64][65];
  const float* inp = in + (size_t)sp * K * HID;
  f16* outp = out + (size_t)sp * K * HID;
  const int k0 = blockIdx.x * 64;
  const int n0 = blockIdx.y * 64;
  const int t = threadIdx.x;
  {
    const int lk = t >> 2;
    const int nq = (t & 3) * 16;
    const float* src = inp + (size_t)(k0 + lk) * HID + n0 + nq;
    #pragma unroll
    for (int i = 0; i < 4; ++i) {
      float4 v = *(const float4*)(src + i * 4);
      tile[lk][nq + i * 4 + 0] = v.x;
      tile[lk][nq + i * 4 + 1] = v.y;
      tile[lk][nq + i * 4 + 2] = v.z;
      tile[lk][nq + i * 4 + 3] = v.w;
    }
  }
  __syncthreads();
  {
    const int ln = t >> 2;
    const int kq = (t & 3) * 16;
    f16* dst = outp + (size_t)(n0 + ln) * K + k0 + kq;
    f16x8 a, b;
    #pragma unroll
    for (int j = 0; j < 8; ++j) a[j] = (f16)tile[kq + j][ln];
    #pragma unroll
    for (int j = 0; j < 8; ++j) b[j] = (f16)tile[kq + 8 + j][ln];
    *(f16x8*)dst = a;
    *(f16x8*)(dst + 8) = b;
  }
}

// ---------------------------------------------------------------------------
// Fused MLP R13 = R7 (best-known, 110us harness) + two cover extensions:
//  - pa: 2 -> 3 rotating sets (issue at c, consume at c+3 => ~3 fat phases
//    ~1300cy HBM cover; R7 had 2 phases ~900cy). Steady VM(16) unchanged
//    (per-phase vmem issue is still 8 gll + 4 pa = 12; newer-than-bS(c) at
//    the wait = 4 pa + 12 = 16).
//  - hidden wS: 2 -> 3 buffers (wS2 = dead bS1-upper), stage chunk c+3
//    after chunk c's MFMA, steady VM(8) => 2-chunk (~300cy) L2 cover
//    (R7's VM(4) gave <1 chunk). Unified stage-after-mfma step shape.
// Everything else is R7 verbatim: 256 thr / 4 waves, 64x64 wave cols,
// bS gll-staged self-owned rows, aS reg-staged fp16 dbuf, 80KB arena.
// ---------------------------------------------------------------------------

__device__ __forceinline__ void zero_acc(f32x4 (&acc)[4][4]) {
  #pragma unroll
  for (int a = 0; a < 4; ++a)
    #pragma unroll
    for (int b = 0; b < 4; ++b)
      #pragma unroll
      for (int j = 0; j < 4; ++j) acc[a][b][j] = 0.f;
}

// L1 weights: bS [256 n][8 slots of 16B]; phys slot p at row r holds k-slot
// p^(r&7). Wave w stages rows w*64..+63 -- the rows it alone reads.
__device__ __forceinline__ void stage_w64(char* bS, const char* wbase, int c,
                                          int w, int lane)
{
  #pragma unroll
  for (int i = 0; i < 8; ++i) {
    const int seg  = w * 8 + i;                 // 0..31
    const int rloc = lane >> 3;                 // 0..7
    const int p    = lane & 7;                  // phys 16B slot
    const int row  = seg * 8 + rloc;            // 0..255
    const int slog = p ^ rloc;                  // logical k-slot (row&7 == rloc)
    const char* gp = wbase + (size_t)row * (NF * 2) + (size_t)c * 128 + slog * 16;
    char* lp = bS + seg * 1024;                 // wave-uniform base
    __builtin_amdgcn_global_load_lds((const GLB u32*)gp, (AS3 u32*)lp, 16, 0, 0);
  }
}

// Hidden weights: [256 n][32 k], phys slot = log ^ ((row>>1)&3). Self-staged.
__device__ __forceinline__ void stage_w32(char* wS, const char* wbase, int c,
                                          int w, int lane)
{
  #pragma unroll
  for (int i = 0; i < 4; ++i) {
    const int seg = w * 4 + i;                  // 0..15
    const int row = seg * 16 + (lane >> 2);     // 0..255
    const int kbp = lane & 3;
    const int kb  = kbp ^ ((row >> 1) & 3);
    const char* gp = wbase + (size_t)row * (HID * 2) + c * 64 + kb * 16;
    char* lp = wS + seg * 1024;
    __builtin_amdgcn_global_load_lds((const GLB u32*)gp, (AS3 u32*)lp, 16, 0, 0);
  }
}

__device__ __forceinline__ void load_pa(float4 (&pa)[4], const float* fsrcT, int c)
{
  #pragma unroll
  for (int j = 0; j < 4; ++j)
    pa[j] = *(const float4*)(fsrcT + c * 64 + j * 4);
}

// Features chunk [64 r][64 k] fp32->fp16 into aS (ds_write).
__device__ __forceinline__ void stage_feat64(char* aS, const float4 (&pa)[4], int t)
{
  const int r = t >> 2;
  #pragma unroll
  for (int wr = 0; wr < 2; ++wr) {
    f16x8 hv;
    const float4 lo = pa[wr * 2 + 0], hi = pa[wr * 2 + 1];
    hv[0]=(f16)lo.x; hv[1]=(f16)lo.y; hv[2]=(f16)lo.z; hv[3]=(f16)lo.w;
    hv[4]=(f16)hi.x; hv[5]=(f16)hi.y; hv[6]=(f16)hi.z; hv[7]=(f16)hi.w;
    const int slog = (t & 3) * 2 + wr;
    const int p = slog ^ (r & 7);
    *(f16x8*)(aS + r * 128 + p * 16) = hv;
  }
}

// L1 compute: one KC=64 chunk, 32 MFMA.
__device__ __forceinline__ void mfma64_a(f32x4 (&acc)[4][4], const char* aS,
                                         const char* bS, int w, int g, int l15)
{
  #pragma unroll
  for (int ks = 0; ks < 2; ++ks) {
    f16x8 af[4], bf[4];
    #pragma unroll
    for (int at = 0; at < 4; ++at) {
      const int rr = at * 16 + l15;
      const int p  = (ks * 4 + g) ^ (rr & 7);
      af[at] = *(const f16x8*)(aS + rr * 128 + p * 16);
    }
    #pragma unroll
    for (int bt = 0; bt < 4; ++bt) {
      const int nn = w * 64 + bt * 16 + l15;
      const int p  = (ks * 4 + g) ^ (nn & 7);
      bf[bt] = *(const f16x8*)(bS + nn * 128 + p * 16);
    }
    #pragma unroll
    for (int at = 0; at < 4; ++at)
      #pragma unroll
      for (int bt = 0; bt < 4; ++bt)
        acc[at][bt] = __builtin_amdgcn_mfma_f32_16x16x32_f16(af[at], bf[bt], acc[at][bt], 0, 0, 0);
  }
}

// Hidden compute: one KC=32 chunk, 16 MFMA.
__device__ __forceinline__ void mfma32_h(f32x4 (&acc)[4][4], const char* hL, int c,
                                         const char* wS, int w, int g, int l15)
{
  f16x8 af[4], bf[4];
  #pragma unroll
  for (int at = 0; at < 4; ++at) {
    const int rr = at * 16 + l15;
    af[at] = *(const f16x8*)(hL + ((rr * 512 + c * 64 + g * 16) ^ ((rr & 7) << 4)));
  }
  #pragma unroll
  for (int bt = 0; bt < 4; ++bt) {
    const int nn = w * 64 + bt * 16 + l15;
    bf[bt] = *(const f16x8*)(wS + nn * 64 + ((g ^ ((nn >> 1) & 3)) * 16));
  }
  #pragma unroll
  for (int at = 0; at < 4; ++at)
    #pragma unroll
    for (int bt = 0; bt < 4; ++bt)
      acc[at][bt] = __builtin_amdgcn_mfma_f32_16x16x32_f16(af[at], bf[bt], acc[at][bt], 0, 0, 0);
}

__device__ __forceinline__ void silu_store(f32x4 (&acc)[4][4],
                                           const float* __restrict__ bias,
                                           char* hL, int w, int lane)
{
  const int g = lane >> 4, l15 = lane & 15;
  #pragma unroll
  for (int bt = 0; bt < 4; ++bt) {
    const int col = w * 64 + bt * 16 + l15;
    const float b = bias[col];
    #pragma unroll
    for (int at = 0; at < 4; ++at) {
      #pragma unroll
      for (int j = 0; j < 4; ++j) {
        const int row = at * 16 + g * 4 + j;   // m89-verified C/D mapping
        float x = acc[at][bt][j] + b;
        x = x * __builtin_amdgcn_rcpf(1.f + __expf(-x));
        *(f16*)(hL + (((row * HID + col) * 2) ^ ((row & 7) << 4))) = (f16)x;
      }
    }
  }
}

// L1 phase: stage feat(c+1) from PAset, gll W1(c+1), refill PAset <- pa(c+4),
// counted wait (forces own gll(c)), compute chunk c, publish, barrier.
#define L1_STEP(c, ASc, ASn, BSc, BSn, PAset, VMN, DOG, DOPA)   \
  do {                                                           \
    stage_feat64(ASn, PAset, t);                                 \
    if (DOG)  stage_w64(BSn, w1s, (c) + 1, w, lane);             \
    if (DOPA) load_pa(PAset, fsrcT, (c) + 4);                    \
    WAIT_VM(VMN); SCHED0();                                      \
    mfma64_a(acc, ASc, BSc, w, g, l15);                          \
    WAIT_LGKM(); BARRIER();                                      \
  } while (0)

// Hidden step: counted wait readies chunk c, compute, drain own reads,
// stage chunk c+3 into the buffer just freed (wave-private, barrier-free).
#define HID_ST(c, WSc, WSstg, wsrc, cs)                          \
  do {                                                           \
    WAIT_VM(8); SCHED0();                                        \
    mfma32_h(acc, hL, c, WSc, w, g, l15);                        \
    WAIT_LGKM(); SCHED0();                                       \
    stage_w32(WSstg, wsrc, cs, w, lane);                         \
  } while (0)

__global__ __launch_bounds__(256, 2) void mlp_fused_kernel(
    const float* __restrict__ feats,
    const float* __restrict__ b1g,
    const float* __restrict__ b2g,
    const float* __restrict__ b3g,
    const float* __restrict__ w4g,
    const float* __restrict__ b4g,
    const int*   __restrict__ sidxg,
    const f16*   __restrict__ w1t,
    const f16*   __restrict__ w2t,
    const f16*   __restrict__ w3t,
    float*       __restrict__ outg)
{
  __shared__ char arena[80 * 1024];
  char* aS0 = arena;                 // L1 features dbuf: 2 x 8 KB
  char* aS1 = arena + 8 * 1024;
  char* bS0 = arena + 16 * 1024;     // L1 weights dbuf: 2 x 32 KB
  char* bS1 = arena + 48 * 1024;
  char* hL  = arena;                 // hidden: h [64][256] fp16, 32 KB
  char* wS0 = arena + 32 * 1024;     // hidden weights: 3 x 16 KB
  char* wS1 = arena + 48 * 1024;
  char* wS2 = arena + 64 * 1024;

  const int s    = blockIdx.y;
  const int row0 = blockIdx.x * TM;
  const int t    = threadIdx.x;
  const int lane = t & 63;
  const int w    = t >> 6;           // 0..3; wave w owns output cols w*64..+63
  const int g    = lane >> 4;
  const int l15  = lane & 15;

  const int gr   = row0 + (t >> 2);
  const bool valid = gr < NPER;
  const int grc  = valid ? gr : (NPER - 1);
  const float* fsrcT = feats + ((size_t)s * NPER + grc) * NF + (t & 3) * 16;
  const char*  w1s   = (const char*)(w1t + (size_t)s * HID * NF);
  const char*  w2s   = (const char*)(w2t + (size_t)s * HID * HID);
  const char*  w3s   = (const char*)(w3t + (size_t)s * HID * HID);

  f32x4 acc[4][4];
  zero_acc(acc);

  // ===== L1 prologue: chunk 0 staged; pa for chunks 1,2,3 in flight =====
  float4 pf[4], paA[4], paB[4], paC[4];
  load_pa(pf, fsrcT, 0);
  stage_w64(bS0, w1s, 0, w, lane);
  load_pa(paA, fsrcT, 1);
  load_pa(paB, fsrcT, 2);
  load_pa(paC, fsrcT, 3);
  stage_feat64(aS0, pf, t);          // compiler-waits pf
  WAIT_LGKM(); BARRIER();

  // ===== L1: 16 phases, KC=64, 3-deep pa rotation, steady VM(16) =====
  L1_STEP(0,  aS0, aS1, bS0, bS1, paA, 20, 1, 1);
  L1_STEP(1,  aS1, aS0, bS1, bS0, paB, 16, 1, 1);
  L1_STEP(2,  aS0, aS1, bS0, bS1, paC, 16, 1, 1);
  L1_STEP(3,  aS1, aS0, bS1, bS0, paA, 16, 1, 1);
  L1_STEP(4,  aS0, aS1, bS0, bS1, paB, 16, 1, 1);
  L1_STEP(5,  aS1, aS0, bS1, bS0, paC, 16, 1, 1);
  L1_STEP(6,  aS0, aS1, bS0, bS1, paA, 16, 1, 1);
  L1_STEP(7,  aS1, aS0, bS1, bS0, paB, 16, 1, 1);
  L1_STEP(8,  aS0, aS1, bS0, bS1, paC, 16, 1, 1);
  L1_STEP(9,  aS1, aS0, bS1, bS0, paA, 16, 1, 1);
  L1_STEP(10, aS0, aS1, bS0, bS1, paB, 16, 1, 1);
  L1_STEP(11, aS1, aS0, bS1, bS0, paC, 16, 1, 1);   // last refill: paC <- 15
  L1_STEP(12, aS0, aS1, bS0, bS1, paA, 12, 1, 0);   // consume pa(13)
  L1_STEP(13, aS1, aS0, bS1, bS0, paB,  8, 1, 0);   // consume pa(14)
  L1_STEP(14, aS0, aS1, bS0, bS1, paC,  8, 1, 0);   // consume pa(15); bS1<-15
  { // phase 15: compute aS1/bS1; early-issue W2 chunk 0 into wS0 (dead bS0-up)
    stage_w32(wS0, w2s, 0, w, lane);
    WAIT_VM(4); SCHED0();
    mfma64_a(acc, aS1, bS1, w, g, l15);
    WAIT_LGKM(); BARRIER();
  }

  // ===== L1 -> L2: write h over dead aS/bS0-lower; fill wS pipeline =====
  silu_store(acc, b1g + s * HID, hL, w, lane);
  zero_acc(acc);
  stage_w32(wS1, w2s, 1, w, lane);   // bS1 dead after phase-15 barrier
  stage_w32(wS2, w2s, 2, w, lane);
  WAIT_LGKM(); BARRIER();

  // ===== Layer 2: 8 chunks, KC=32, barrier-free, 3-buf wS, VM(8) =====
  HID_ST(0, wS0, wS0, w2s, 3);
  HID_ST(1, wS1, wS1, w2s, 4);
  HID_ST(2, wS2, wS2, w2s, 5);
  HID_ST(3, wS0, wS0, w2s, 6);
  HID_ST(4, wS1, wS1, w2s, 7);
  HID_ST(5, wS2, wS2, w3s, 0);       // cross into W3 prefetch
  HID_ST(6, wS0, wS0, w3s, 1);
  HID_ST(7, wS1, wS1, w3s, 2);
  BARRIER();                         // all waves done reading hL
  silu_store(acc, b2g + s * HID, hL, w, lane);
  zero_acc(acc);
  WAIT_LGKM(); BARRIER();            // hL published

  // ===== Layer 3: 8 chunks; in flight: 0(wS2),1(wS0),2(wS1) =====
  HID_ST(0, wS2, wS2, w3s, 3);
  HID_ST(1, wS0, wS0, w3s, 4);
  HID_ST(2, wS1, wS1, w3s, 5);
  HID_ST(3, wS2, wS2, w3s, 6);
  HID_ST(4, wS0, wS0, w3s, 7);
  { WAIT_VM(8); SCHED0(); mfma32_h(acc, hL, 5, wS1, w, g, l15); }
  { WAIT_VM(4); SCHED0(); mfma32_h(acc, hL, 6, wS2, w, g, l15); }
  { WAIT_VM(0); SCHED0(); mfma32_h(acc, hL, 7, wS0, w, g, l15); }
  BARRIER();
  silu_store(acc, b3g + s * HID, hL, w, lane);
  WAIT_LGKM(); BARRIER();

  // ===== Layer 4: e = h @ W4 + b4; segment-sum via atomicAdd =====
  {
    const int row = t >> 2;
    const int q   = t & 3;
    const float* w4 = w4g + s * HID;
    float sum = 0.f;
    #pragma unroll
    for (int j8 = 0; j8 < 64; j8 += 8) {
      const int k = q * 64 + j8;
      f16x8 hv = *(const f16x8*)(hL + (((row * HID + k) * 2) ^ ((row & 7) << 4)));
      float4 wa = *(const float4*)(w4 + k);
      float4 wb = *(const float4*)(w4 + k + 4);
      sum += (float)hv[0] * wa.x + (float)hv[1] * wa.y + (float)hv[2] * wa.z + (float)hv[3] * wa.w
           + (float)hv[4] * wb.x + (float)hv[5] * wb.y + (float)hv[6] * wb.z + (float)hv[7] * wb.w;
    }
    sum += __shfl_xor(sum, 1);
    sum += __shfl_xor(sum, 2);
    if (q == 0 && valid) {
      atomicAdd(&outg[sidxg[s * NPER + gr]], sum + b4g[s]);
    }
  }
}

// ---------------------------------------------------------------------------
extern "C" void kernel_launch(void* const* d_in, const int* in_sizes, int n_in,
                              void* d_out, int out_size, void* d_ws, size_t ws_size,
                              hipStream_t stream)
{
  const float* feats = (const float*)d_in[0];
  const float* W1    = (const float*)d_in[1];
  const float* b1    = (const float*)d_in[2];
  const float* W2    = (const float*)d_in[3];
  const float* b2    = (const float*)d_in[4];
  const float* W3    = (const float*)d_in[5];
  const float* b3    = (const float*)d_in[6];
  const float* W4    = (const float*)d_in[7];
  const float* b4    = (const float*)d_in[8];
  const int*   sidx  = (const int*)d_in[9];
  float* out = (float*)d_out;

  f16* w1t = (f16*)d_ws;                              // [S][256][1024] fp16
  f16* w2t = w1t + (size_t)S_ * HID * NF;             // [S][256][256]  fp16
  f16* w3t = w2t + (size_t)S_ * HID * HID;            // [S][256][256]  fp16

  hipMemsetAsync(d_out, 0, NSTRUCT * sizeof(float), stream);
  transpose_all_kernel<<<dim3(16, 4, 12), 256, 0, stream>>>(W1, W2, W3, w1t, w2t, w3t);
  mlp_fused_kernel<<<dim3((NPER + TM - 1) / TM, S_), 256, 0, stream>>>(
      feats, b1, b2, b3, W4, b4, sidx, w1t, w2t, w3t, out);
}